// Round 1
// baseline (674.529 us; speedup 1.0000x reference)
//
#include <hip/hip_runtime.h>
#include <hip/hip_bf16.h>
#include <math.h>

typedef __attribute__((ext_vector_type(8))) short short8;
typedef __attribute__((ext_vector_type(4))) float f32x4;

#define C_IN 128
#define OC_ 128
#define BB 8
#define KBANK 4

__device__ __forceinline__ unsigned short f2bf(float f) {
  union { float f; unsigned int u; } v; v.f = f;
  unsigned int u = v.u;
  unsigned int r = u + 0x7fffu + ((u >> 16) & 1u);
  return (unsigned short)(r >> 16);
}

// ---------------- Kernel 1: per-(b,c) global mean (8 parallel streams) -----
__global__ __launch_bounds__(256) void k_pool(const float* __restrict__ x,
                                              float* __restrict__ pooled) {
  int plane = blockIdx.x;  // 0..1023 = b*128+c
  const float4* p = (const float4*)(x + ((size_t)plane << 16));
  float s0 = 0.f, s1 = 0.f, s2 = 0.f, s3 = 0.f;
  float s4 = 0.f, s5 = 0.f, s6 = 0.f, s7 = 0.f;
  for (int i = threadIdx.x; i < 2048; i += 256) {
    float4 a0 = p[i];
    float4 a1 = p[i + 2048];
    float4 a2 = p[i + 4096];
    float4 a3 = p[i + 6144];
    float4 a4 = p[i + 8192];
    float4 a5 = p[i + 10240];
    float4 a6 = p[i + 12288];
    float4 a7 = p[i + 14336];
    s0 += (a0.x + a0.y) + (a0.z + a0.w);
    s1 += (a1.x + a1.y) + (a1.z + a1.w);
    s2 += (a2.x + a2.y) + (a2.z + a2.w);
    s3 += (a3.x + a3.y) + (a3.z + a3.w);
    s4 += (a4.x + a4.y) + (a4.z + a4.w);
    s5 += (a5.x + a5.y) + (a5.z + a5.w);
    s6 += (a6.x + a6.y) + (a6.z + a6.w);
    s7 += (a7.x + a7.y) + (a7.z + a7.w);
  }
  float s = ((s0 + s1) + (s2 + s3)) + ((s4 + s5) + (s6 + s7));
  #pragma unroll
  for (int off = 32; off > 0; off >>= 1) s += __shfl_down(s, off);
  __shared__ float red[4];
  if ((threadIdx.x & 63) == 0) red[threadIdx.x >> 6] = s;
  __syncthreads();
  if (threadIdx.x == 0)
    pooled[plane] = (red[0] + red[1] + red[2] + red[3]) * (1.0f / 65536.0f);
}

// ---------------- Kernel 2: attention softmax + dynamic kernel + bf16 pw ----
__global__ void k_prep(const float* __restrict__ pooled,
                       const float* __restrict__ attn_w,
                       const float* __restrict__ attn_b,
                       const float* __restrict__ bank,   // [4][128][1][3][3]
                       const float* __restrict__ pw_w,   // [128][128]
                       float* __restrict__ dynk,         // out: [8][128][9]
                       unsigned short* __restrict__ pwb) // out: [128][128] bf16
{
  __shared__ float attn_s[BB][KBANK];
  int tid = threadIdx.x;
  {
    int pr = tid >> 3, g = tid & 7;
    int b = pr >> 2, k = pr & 3;
    float s = 0.f;
    #pragma unroll
    for (int j = 0; j < 16; ++j) {
      int c = g * 16 + j;
      s += pooled[b * C_IN + c] * attn_w[k * C_IN + c];
    }
    s += __shfl_xor(s, 1);
    s += __shfl_xor(s, 2);
    s += __shfl_xor(s, 4);
    if (g == 0) attn_s[b][k] = s + attn_b[k];
  }
  __syncthreads();
  if (tid < BB) {
    int b = tid;
    float l0 = attn_s[b][0], l1 = attn_s[b][1], l2 = attn_s[b][2], l3 = attn_s[b][3];
    float m = fmaxf(fmaxf(l0, l1), fmaxf(l2, l3));
    float e0 = expf(l0 - m), e1 = expf(l1 - m), e2 = expf(l2 - m), e3 = expf(l3 - m);
    float inv = 1.0f / (e0 + e1 + e2 + e3);
    attn_s[b][0] = e0 * inv; attn_s[b][1] = e1 * inv;
    attn_s[b][2] = e2 * inv; attn_s[b][3] = e3 * inv;
  }
  __syncthreads();
  for (int i = tid; i < BB * C_IN * 9; i += 256) {
    int b = i / (C_IN * 9);
    int rem = i - b * (C_IN * 9);
    float v = 0.f;
    #pragma unroll
    for (int k = 0; k < KBANK; ++k) v += attn_s[b][k] * bank[k * (C_IN * 9) + rem];
    dynk[i] = v;
  }
  for (int i = tid; i < OC_ * C_IN; i += 256) pwb[i] = f2bf(pw_w[i]);
}

// ---------------- staging loaders (register prefetch targets) --------------
__device__ __forceinline__ void load18(const float* __restrict__ g, bool ok,
                                       bool eL, bool eR, float* v) {
  if (ok) {
    float4 a = *(const float4*)(g + 1);
    float4 b = *(const float4*)(g + 5);
    float4 c = *(const float4*)(g + 9);
    float4 d = *(const float4*)(g + 13);
    v[0] = eL ? g[0] : 0.f;
    v[17] = eR ? g[17] : 0.f;
    v[1] = a.x; v[2] = a.y; v[3] = a.z; v[4] = a.w;
    v[5] = b.x; v[6] = b.y; v[7] = b.z; v[8] = b.w;
    v[9] = c.x; v[10] = c.y; v[11] = c.z; v[12] = c.w;
    v[13] = d.x; v[14] = d.y; v[15] = d.z; v[16] = d.w;
  } else {
    #pragma unroll
    for (int j = 0; j < 18; ++j) v[j] = 0.f;
  }
}

__device__ __forceinline__ void load9(const float* __restrict__ g, bool ok,
                                      bool eL, bool eR, int hf, float* u) {
  if (ok) {
    if (hf == 0) {  // floats 0..8 of the 18-float row
      float4 a = *(const float4*)(g + 1);
      float4 b = *(const float4*)(g + 5);
      u[0] = eL ? g[0] : 0.f;
      u[1] = a.x; u[2] = a.y; u[3] = a.z; u[4] = a.w;
      u[5] = b.x; u[6] = b.y; u[7] = b.z; u[8] = b.w;
    } else {        // floats 9..17
      float4 a = *(const float4*)(g + 9);
      float4 b = *(const float4*)(g + 13);
      u[0] = a.x; u[1] = a.y; u[2] = a.z; u[3] = a.w;
      u[4] = b.x; u[5] = b.y; u[6] = b.z; u[7] = b.w;
      u[8] = eR ? g[17] : 0.f;
    }
  } else {
    #pragma unroll
    for (int j = 0; j < 9; ++j) u[j] = 0.f;
  }
}

// ---------------- Kernel 3: fused depthwise 3x3 + pointwise MFMA ----------
// 1-D grid, XCD-swizzled: hw wg i lands on XCD i%8 -> b = i&7 keeps each
// batch image (512 tiles) on one XCD so halo lines are L2 hits.
// Pipelined: chunk k+1's x rows prefetched into registers during chunk k.
__global__ __launch_bounds__(256, 3) void k_main(
    const float* __restrict__ x,
    const float* __restrict__ dynk,
    const unsigned short* __restrict__ pwb,
    const float* __restrict__ pw_b,
    float* __restrict__ out) {
  constexpr int RS = 18;           // xs row stride (dwords)
  constexpr int PS = 181;          // per-channel plane stride (ODD: bank spread)
  __shared__ float xs[32 * PS];             // 23168 B
  __shared__ unsigned short dws[128 * 40];  // [pixel][k_local pad40] 10240 B

  const int b  = blockIdx.x & 7;           // image -> XCD
  const int t  = blockIdx.x >> 3;          // 0..511 tile within image
  const int bx = t & 15;
  const int by = t >> 4;
  const int h0 = by * 8;
  const int w0 = bx * 16;

  const int tid  = threadIdx.x;
  const int wv   = tid >> 6;
  const int lane = tid & 63;
  const int quad = lane >> 4;
  const int l15  = lane & 15;
  const int cl   = tid & 31;  // depthwise: chunk-local channel
  const int prow = tid >> 5;  // depthwise: pixel row 0..7

  // primary staging: (c0 = tid>>3, r0 = tid&7) -> rows 0..7 of 32 channels
  const int c0 = tid >> 3, r0 = tid & 7;
  const int gh0 = h0 - 1 + r0;
  const bool ok0 = (unsigned)gh0 < 256u;
  const float* g0 = x + (((size_t)(b * C_IN + c0)) << 16)
                      + (size_t)(ok0 ? gh0 : 0) * 256 + (w0 - 1);
  float* s0p = xs + c0 * PS + r0 * RS;
  // secondary staging (tid<128): half-rows of rows 8,9 -> 9 floats/thread
  const bool has2 = tid < 128;
  const int c1 = tid >> 2;
  const int hf = (tid >> 1) & 1;
  const int r1 = 8 + (tid & 1);
  const int gh1 = h0 - 1 + r1;
  const bool ok1 = (unsigned)gh1 < 256u;
  const float* g1 = x + (((size_t)(b * C_IN + c1)) << 16)
                      + (size_t)(ok1 ? gh1 : 0) * 256 + (w0 - 1);
  float* s1p = xs + c1 * PS + r1 * RS + hf * 9;

  const bool wL = (w0 > 0), wR = (w0 < 240);

  f32x4 acc[2][8];
  #pragma unroll
  for (int mt = 0; mt < 2; ++mt)
    #pragma unroll
    for (int nt = 0; nt < 8; ++nt)
      acc[mt][nt] = (f32x4){0.f, 0.f, 0.f, 0.f};

  // prologue: prefetch chunk 0 into registers
  float vp[18], up[9];
  load18(g0, ok0, wL, wR, vp);
  if (has2) load9(g1, ok1, wL, wR, hf, up);

  #pragma unroll
  for (int kc = 0; kc < 4; ++kc) {
    __syncthreads();  // depthwise(kc-1) xs reads & MFMA(kc-1) dws reads done
    // drain current prefetch registers -> LDS
    #pragma unroll
    for (int j = 0; j < 18; ++j) s0p[j] = vp[j];
    if (has2) {
      #pragma unroll
      for (int j = 0; j < 9; ++j) s1p[j] = up[j];
    }
    // issue next chunk's global loads: latency hides under compute below
    if (kc < 3) {
      g0 += (size_t)32 << 16;
      g1 += (size_t)32 << 16;
      load18(g0, ok0, wL, wR, vp);
      if (has2) load9(g1, ok1, wL, wR, hf, up);
    }
    // per-chunk small loads (L1/L2-hot), issued before the barrier
    float k9[9];
    {
      const float* kp = dynk + (size_t)(b * C_IN + kc * 32 + cl) * 9;
      #pragma unroll
      for (int q = 0; q < 9; ++q) k9[q] = kp[q];
    }
    short8 af0 = *(const short8*)(pwb + ((size_t)(wv * 32 + l15) * C_IN + kc * 32 + quad * 8));
    short8 af1 = *(const short8*)(pwb + ((size_t)(wv * 32 + 16 + l15) * C_IN + kc * 32 + quad * 8));
    __syncthreads();  // xs(kc) ready
    // ---- depthwise: thread = (channel cl, pixel row prow), 16 cols
    float accd[16];
    #pragma unroll
    for (int col = 0; col < 16; ++col) accd[col] = 0.f;
    const float* xp = &xs[cl * PS + prow * RS];
    #pragma unroll
    for (int i = 0; i < 3; ++i) {
      float xr[18];
      const float* rp = xp + i * RS;
      #pragma unroll
      for (int j = 0; j < 18; ++j) xr[j] = rp[j];
      float cc0 = k9[3 * i], cc1 = k9[3 * i + 1], cc2 = k9[3 * i + 2];
      #pragma unroll
      for (int col = 0; col < 16; ++col)
        accd[col] = fmaf(cc0, xr[col], fmaf(cc1, xr[col + 1], fmaf(cc2, xr[col + 2], accd[col])));
    }
    #pragma unroll
    for (int col = 0; col < 16; ++col)
      dws[(prow * 16 + col) * 40 + cl] = f2bf(accd[col]);
    __syncthreads();  // dws(kc) ready
    // ---- MFMA: 16 per wave per chunk
    #pragma unroll
    for (int nt = 0; nt < 8; ++nt) {
      short8 bfrag = *(const short8*)&dws[(nt * 16 + l15) * 40 + quad * 8];
      acc[0][nt] = __builtin_amdgcn_mfma_f32_16x16x32_bf16(af0, bfrag, acc[0][nt], 0, 0, 0);
      acc[1][nt] = __builtin_amdgcn_mfma_f32_16x16x32_bf16(af1, bfrag, acc[1][nt], 0, 0, 0);
    }
  }
  // ---- epilogue: non-temporal stores keep x resident in L3
  #pragma unroll
  for (int mt = 0; mt < 2; ++mt) {
    #pragma unroll
    for (int r = 0; r < 4; ++r) {
      int o = wv * 32 + mt * 16 + quad * 4 + r;
      float bias = pw_b[o];
      size_t obase = ((size_t)(b * OC_ + o)) << 16;
      #pragma unroll
      for (int nt = 0; nt < 8; ++nt)
        __builtin_nontemporal_store(acc[mt][nt][r] + bias,
                                    &out[obase + ((h0 + nt) << 8) + (w0 + l15)]);
    }
  }
}

extern "C" void kernel_launch(void* const* d_in, const int* in_sizes, int n_in,
                              void* d_out, int out_size, void* d_ws, size_t ws_size,
                              hipStream_t stream) {
  const float* x      = (const float*)d_in[0];
  const float* bank   = (const float*)d_in[1];
  const float* attn_w = (const float*)d_in[2];
  const float* attn_b = (const float*)d_in[3];
  const float* pw_w   = (const float*)d_in[4];
  const float* pw_b   = (const float*)d_in[5];
  float* out = (float*)d_out;

  char* ws = (char*)d_ws;
  float* pooled       = (float*)ws;                       // 1024 f32
  float* dynk         = (float*)(ws + 4096);              // 9216 f32
  unsigned short* pwb = (unsigned short*)(ws + 4096 + 36864); // 16384 bf16

  k_pool<<<1024, 256, 0, stream>>>(x, pooled);
  k_prep<<<1, 256, 0, stream>>>(pooled, attn_w, attn_b, bank, pw_w, dynk, pwb);
  k_main<<<4096, 256, 0, stream>>>(x, dynk, pwb, pw_b, out);
}